// Round 5
// baseline (291.345 us; speedup 1.0000x reference)
//
#include <hip/hip_runtime.h>

// LSTM_67980742362036: 2-layer LSTM (B=4096, T=200, I=32, H=6) + linear head.
// R13 = R12 split with both halves re-engineered:
//  proj_k2: LDS-free projection. R12's proj_k was LDS-read-throughput bound
//    (96 ds_read_b128 per timestep per lane ~ 36us of LDS pipe). Weights are
//    3KB and wave-uniform -> scalar (SGPR) loads; x row in regs; one lane per
//    (b,t) row, exact 12800x64 grid; coalesced 128B read / 96B write per lane.
//  scan_k3: R12 16-lane-per-batch scan with the 12 ds_swizzle broadcasts
//    (DS-pipe, ~120cy latency, the suspected 764cy/step driver) replaced by
//    15 DPP row_ror rotations (pure VALU). arg[g] = base + sum_m Wq[g][m] *
//    rot_m(h_prev): per-lane weight table gathered AT INIT using a probed
//    srole[m] = mov_dpp(lane_id) -> correctness independent of the HW's
//    rotate-direction convention. Zero LDS, zero barriers, 1024x64 grid.
// Structure (roles, xp4 stream+pipeline, peel, tail, output head) copied
// verbatim from the verified R12 scan. Fallback: proven R8 kernel.

#define TLEN  200
#define ISZ   32
#define HSZ   6
#define WPITCH 36

// ---- fallback (R8) LDS layout ----
#define RPITCH 25
#define RING_DW (64 * RPITCH)
#define FWOFF  RING_DW
#define FBOFF  (FWOFF + 24 * WPITCH)
#define FLDS_DW (FBOFF + 24)           // 9952 B

#define XP4_COUNT ((size_t)4096 * TLEN * 6)          // float4 elements
#define WS_REQ    ((XP4_COUNT + 6) * 16)             // + bias4 table

__device__ __forceinline__ float fast_sig(float x) {
    return __builtin_amdgcn_rcpf(1.0f + __expf(-x));
}
__device__ __forceinline__ float tanh_s(float x) {     // tanh via 2*sig(2x)-1
    return fmaf(2.0f, fast_sig(x + x), -1.0f);
}
__device__ __forceinline__ float rl(float v, int l) {
    return __int_as_float(__builtin_amdgcn_readlane(__float_as_int(v), l));
}
template <int CTRL>
__device__ __forceinline__ float qperm(float v) {
    return __int_as_float(__builtin_amdgcn_mov_dpp(__float_as_int(v), CTRL, 0xf, 0xf, true));
}
template <int OFF>
__device__ __forceinline__ float swz(float v) {        // BitMode group-broadcast
    return __int_as_float(__builtin_amdgcn_ds_swizzle(__float_as_int(v), OFF));
}
template <int M>
__device__ __forceinline__ float rotf(float v) {       // row_ror:M (16-lane row)
    return __int_as_float(__builtin_amdgcn_mov_dpp(__float_as_int(v), 0x120 + M, 0xf, 0xf, true));
}
__device__ __forceinline__ float dot4(float4 w, float4 v) {
    return fmaf(w.x, v.x, fmaf(w.y, v.y, fmaf(w.z, v.z, w.w * v.w)));
}

// ======================= kernel 1: LDS-free projection =======================
__global__ __launch_bounds__(64) void proj_k2(
    const float* __restrict__ x,    const float* __restrict__ Wih0,
    const float* __restrict__ bih0, const float* __restrict__ bhh0,
    const float* __restrict__ bih1, const float* __restrict__ bhh1,
    float4* __restrict__ xp4)       // [b*200+t][u] (i,f,g,o); bias4 at XP4_COUNT
{
    const int lane = threadIdx.x;
    const size_t n = (size_t)blockIdx.x * 64 + lane;   // row index b*200+t (exact grid)

    if (blockIdx.x == 0 && lane < 24) {                // layer-1 folded bias table
        const int u = lane % 6, g = lane / 6;
        ((float*)(xp4 + XP4_COUNT))[u * 4 + g] = bih1[g * 6 + u] + bhh1[g * 6 + u];
    }

    const float4* xr = (const float4*)(x + n * ISZ);
    float4 xv[8];
#pragma unroll
    for (int q = 0; q < 8; ++q) xv[q] = xr[q];

    float acc[24];
#pragma unroll
    for (int r = 0; r < 24; ++r) {
        float a = bih0[r] + bhh0[r];                   // uniform -> scalar loads
        const float* wr = Wih0 + r * ISZ;              // uniform row -> SGPR stream
#pragma unroll
        for (int q = 0; q < 8; ++q) {
            a = fmaf(wr[q * 4 + 0], xv[q].x, a);
            a = fmaf(wr[q * 4 + 1], xv[q].y, a);
            a = fmaf(wr[q * 4 + 2], xv[q].z, a);
            a = fmaf(wr[q * 4 + 3], xv[q].w, a);
        }
        acc[r] = a;
    }
    float4* dst = xp4 + n * 6;                         // 96B contiguous per lane
#pragma unroll
    for (int u = 0; u < 6; ++u)
        dst[u] = make_float4(acc[u], acc[6 + u], acc[12 + u], acc[18 + u]);
}

// ======================= kernel 2: DPP-rotation scan =======================
__global__ __launch_bounds__(64) void scan_k3(
    const float* __restrict__ Whh0, const float* __restrict__ Wih1,
    const float* __restrict__ Whh1, const float* __restrict__ Wlin,
    const float* __restrict__ blin, const float4* __restrict__ xp4,
    float* __restrict__ out)
{
    const int lane = threadIdx.x;
    const int role = lane & 15;
    const int grp  = lane >> 4;
    const int b    = blockIdx.x * 4 + grp;

    // ---- probe the HW rotation: srole[m] = role whose value rot_m delivers ----
    int sr[16];
    sr[0] = role;
#define PRB(M) sr[M] = __builtin_amdgcn_mov_dpp(lane, 0x120 + M, 0xf, 0xf, true) & 15;
    PRB(1)  PRB(2)  PRB(3)  PRB(4)  PRB(5)  PRB(6)  PRB(7)
    PRB(8)  PRB(9)  PRB(10) PRB(11) PRB(12) PRB(13) PRB(14) PRB(15)
#undef PRB

    // ---- per-lane weight table Wq[gate][m] for the rotation-accumulate ----
    // role<6 : L0 unit u=role : arg = xp.gate + sum Whh0[g6u][s]*h0p[s]
    // 6..11  : L1 unit u=role-6: arg = bias1 + Wih1[g6u]*h0p + Whh1[g6u]*h1p
    // 12..15 : inert (all weights 0; base = bias cell -> finite garbage state)
    const int lt = (role < 6) ? 0 : (role < 12 ? 1 : 2);
    const int u  = (role < 6) ? role : (role < 12 ? role - 6 : 0);
    float Wq[4][16];
#pragma unroll
    for (int g = 0; g < 4; ++g)
#pragma unroll
        for (int m = 0; m < 16; ++m) {
            const int s = sr[m];
            float w = 0.0f;
            if (lt == 0) {
                if (s < 6) w = Whh0[(g * 6 + u) * 6 + s];
            } else if (lt == 1) {
                if (s < 6)       w = Wih1[(g * 6 + u) * 6 + s];
                else if (s < 12) w = Whh1[(g * 6 + u) * 6 + (s - 6)];
            }
            Wq[g][m] = w;
        }

    // ---- xp stream (verbatim R12): L0 lanes walk xp4; others pin bias cell ----
    const float4* P;
    int ST;
    if (role < 6) { P = xp4 + (size_t)b * TLEN * 6 + role; ST = 6; }
    else          { P = xp4 + XP4_COUNT + (role < 12 ? role - 6 : 0); ST = 0; }

    float4 q0 = P[0], q1 = P[ST], q2 = P[2 * ST], q3 = P[3 * ST];
    P += 4 * ST;

    float c = 0.0f, h = 0.0f;

#define GATE(G, BASE) ({ \
    float _s0 = fmaf(Wq[G][0], h, (BASE)); \
    _s0 = fmaf(Wq[G][2],  hm2,  _s0); \
    _s0 = fmaf(Wq[G][4],  hm4,  _s0); \
    _s0 = fmaf(Wq[G][6],  hm6,  _s0); \
    _s0 = fmaf(Wq[G][8],  hm8,  _s0); \
    _s0 = fmaf(Wq[G][10], hm10, _s0); \
    _s0 = fmaf(Wq[G][12], hm12, _s0); \
    _s0 = fmaf(Wq[G][14], hm14, _s0); \
    float _s1 = fmaf(Wq[G][1], hm1, Wq[G][3] * hm3); \
    _s1 = fmaf(Wq[G][5],  hm5,  _s1); \
    _s1 = fmaf(Wq[G][7],  hm7,  _s1); \
    _s1 = fmaf(Wq[G][9],  hm9,  _s1); \
    _s1 = fmaf(Wq[G][11], hm11, _s1); \
    _s1 = fmaf(Wq[G][13], hm13, _s1); \
    _s1 = fmaf(Wq[G][15], hm15, _s1); \
    _s0 + _s1; })

#define STEP(XQ) do { \
    const float hm1 = rotf<1>(h),   hm2 = rotf<2>(h),   hm3 = rotf<3>(h); \
    const float hm4 = rotf<4>(h),   hm5 = rotf<5>(h),   hm6 = rotf<6>(h); \
    const float hm7 = rotf<7>(h),   hm8 = rotf<8>(h),   hm9 = rotf<9>(h); \
    const float hm10 = rotf<10>(h), hm11 = rotf<11>(h), hm12 = rotf<12>(h); \
    const float hm13 = rotf<13>(h), hm14 = rotf<14>(h), hm15 = rotf<15>(h); \
    const float A0 = GATE(0, (XQ).x); \
    const float A1 = GATE(1, (XQ).y); \
    const float A2 = GATE(2, (XQ).z); \
    const float A3 = GATE(3, (XQ).w); \
    const float ig = fast_sig(A0), fg = fast_sig(A1); \
    const float gg = tanh_s(A2),   og = fast_sig(A3); \
    c = fmaf(fg, c, ig * gg); \
    h = og * tanh_s(c); \
} while (0)

#define STEPR(QV) do { const float4 _xq = QV; QV = *P; P += ST; STEP(_xq); } while (0)

    // s = 0 peel; then erase L1/inert phantom state (h1(-1) = 0)  [R12 verbatim]
    STEPR(q0);
    h = (role < 6) ? h : 0.0f;
    c = (role < 6) ? c : 0.0f;

    // s = 1..192 (48 x 4 rotating 4-deep prefetch)
#pragma unroll 1
    for (int m = 0; m < 48; ++m) {
        STEPR(q1); STEPR(q2); STEPR(q3); STEPR(q0);
    }
    // s = 193..200 tail  [R12 verbatim]
    STEPR(q1); STEPR(q2); STEPR(q3);
    STEP(q0); STEP(q1); STEP(q2); STEP(q3);
    STEP(q0);

    // linear head: h2_last lives on roles 6..11  [R12 verbatim]
    {
        const float f0 = swz<0x0D0>(h), f1 = swz<0x0F0>(h), f2 = swz<0x110>(h);
        const float f3 = swz<0x130>(h), f4 = swz<0x150>(h), f5 = swz<0x170>(h);
        float s = blin[0];
        s = fmaf(Wlin[0], f0, s); s = fmaf(Wlin[1], f1, s);
        s = fmaf(Wlin[2], f2, s); s = fmaf(Wlin[3], f3, s);
        s = fmaf(Wlin[4], f4, s); s = fmaf(Wlin[5], f5, s);
        if (role == 0) out[b] = s;
    }
#undef STEP
#undef STEPR
#undef GATE
}

// ======================= fallback: proven R8 kernel (135.5 us) =======================
__global__ __launch_bounds__(64) void lstm_fb(
    const float* __restrict__ x,
    const float* __restrict__ Wih0, const float* __restrict__ Whh0,
    const float* __restrict__ bih0, const float* __restrict__ bhh0,
    const float* __restrict__ Wih1, const float* __restrict__ Whh1,
    const float* __restrict__ bih1, const float* __restrict__ bhh1,
    const float* __restrict__ Wlin, const float* __restrict__ blin,
    float* __restrict__ out)
{
    __shared__ float lds[FLDS_DW];

    const int lane = threadIdx.x;
    const int b    = blockIdx.x;

    const int o = lane & 1;
    const int L = lane >> 1;

    const bool loHalf = (lane < 32);
    const int  p  = lane & 3;
    const int  jq = (lane & 31) >> 2;
    const int  j  = (jq < HSZ) ? jq : 0;
    const int  r  = 6 * p + j;

#define LDSW(ROW, KCQ) (*(const float4*)&lds[FWOFF + (o * 12 + (ROW)) * WPITCH + ((KCQ) << 2)])

#pragma unroll
    for (int k = 0; k < 13; ++k) {
        const int idx = lane + (k << 6);
        if (idx < 768) {
            const int row = idx >> 5, kk = idx & 31;
            lds[FWOFF + row * WPITCH + kk] = Wih0[idx];
        } else if (idx < 792) {
            lds[FBOFF + idx - 768] = bih0[idx - 768] + bhh0[idx - 768];
        }
    }

    float WA[6], WB[6], base1 = 0.0f, sgc = 1.0f, tgc = 0.0f;
#pragma unroll
    for (int k = 0; k < 6; ++k) { WA[k] = 0.0f; WB[k] = 0.0f; }
    if (loHalf) {
#pragma unroll
        for (int k = 0; k < 6; ++k) WA[k] = Whh0[r * 6 + k];
    } else {
#pragma unroll
        for (int k = 0; k < 6; ++k) { WA[k] = Wih1[r * 6 + k]; WB[k] = Whh1[r * 6 + k]; }
        base1 = bih1[r] + bhh1[r];
    }
    if (p == 2) {
#pragma unroll
        for (int k = 0; k < 6; ++k) { WA[k] *= 2.0f; WB[k] *= 2.0f; }
        base1 *= 2.0f; sgc = 2.0f; tgc = -1.0f;
    }

    const float* xb = x + (size_t)b * TLEN * ISZ;

#pragma unroll
    for (int w01 = 0; w01 < 2; ++w01) {
        const int t = (w01 << 5) + L;
        const float4* xr4 = (const float4*)(xb + t * ISZ);
        float4 xw[8];
#pragma unroll
        for (int q = 0; q < 8; ++q) xw[q] = xr4[q];
        float a0c[12];
#pragma unroll
        for (int jj = 0; jj < 12; ++jj) a0c[jj] = 0.0f;
#pragma unroll
        for (int kc = 0; kc < 8; ++kc)
#pragma unroll
            for (int jj = 0; jj < 12; ++jj)
                a0c[jj] += dot4(LDSW(jj, kc), xw[kc]);
#pragma unroll
        for (int jj = 0; jj < 12; ++jj) {
            float v = a0c[jj] + lds[FBOFF + o * 12 + jj];
            if (jj < 6) v = (o == 1) ? v * 2.0f : v;
            lds[t * RPITCH + o * 12 + jj] = v;
        }
    }

    float acc[12];
#pragma unroll
    for (int jj = 0; jj < 12; ++jj) acc[jj] = 0.0f;
    const float* pc = xb + (size_t)min(64 + L, TLEN - 1) * ISZ;
    const float* pn = xb + (size_t)min(96 + L, TLEN - 1) * ISZ;
    float4 f0, f1;
    f1 = *((const float4*)pc);
    float4 Wp0 = LDSW(0, 0), Wp1 = LDSW(1, 0), Wp2 = LDSW(2, 0);

    float c = 0.0f, h = 0.0f;
    float xp_cur = lds[r];

#define KC_HEAD(KC) do { \
    f0 = f1; \
    const float4* _srcp = ((KC) < 7) ? ((const float4*)pc + (KC) + 1) \
                                     : ((const float4*)pn); \
    f1 = *_srcp; \
} while (0)

#define SPREAD_STEP(RT, KC) do { \
    acc[3*(RT)+0] += dot4(Wp0, f0); \
    acc[3*(RT)+1] += dot4(Wp1, f0); \
    acc[3*(RT)+2] += dot4(Wp2, f0); \
    const int _rtn = ((RT) + 1) & 3; \
    const int _kcn = ((RT) == 3) ? (((KC) + 1) & 7) : (KC); \
    Wp0 = LDSW(3*_rtn + 0, _kcn); \
    Wp1 = LDSW(3*_rtn + 1, _kcn); \
    Wp2 = LDSW(3*_rtn + 2, _kcn); \
} while (0)

#define SCAN_STEP(ITV) do { \
    const float h10=rl(h,0),  h11=rl(h,4),  h12=rl(h,8); \
    const float h13=rl(h,12), h14=rl(h,16), h15=rl(h,20); \
    const float h20=rl(h,32), h21=rl(h,36), h22=rl(h,40); \
    const float h23=rl(h,44), h24=rl(h,48), h25=rl(h,52); \
    const float _xn = lds[(((ITV) + 1) & 63) * RPITCH + r]; \
    const float _g0 = loHalf ? xp_cur : base1; \
    const float _a0 = fmaf(WA[0],h10, fmaf(WA[2],h12, fmaf(WA[4],h14, _g0))); \
    const float _a1 = fmaf(WA[1],h11, fmaf(WA[3],h13, WA[5]*h15)); \
    const float _b0 = fmaf(WB[0],h20, fmaf(WB[2],h22, WB[4]*h24)); \
    const float _b1 = fmaf(WB[1],h21, fmaf(WB[3],h23, WB[5]*h25)); \
    const float _g  = (_a0 + _a1) + (_b0 + _b1); \
    const float _aG = fmaf(sgc, fast_sig(_g), tgc); \
    const float _iq = qperm<0x00>(_aG), _fq = qperm<0x55>(_aG); \
    const float _gq = qperm<0xAA>(_aG), _oq = qperm<0xFF>(_aG); \
    c = fmaf(_fq, c, _iq * _gq); \
    const float _th = fmaf(2.0f, fast_sig(2.0f * c), -1.0f); \
    h = _oq * _th; \
    xp_cur = _xn; \
    if ((ITV) == 200) { \
        float _s = blin[0]; \
        _s = fmaf(Wlin[0], rl(h, 32), _s); \
        _s = fmaf(Wlin[1], rl(h, 36), _s); \
        _s = fmaf(Wlin[2], rl(h, 40), _s); \
        _s = fmaf(Wlin[3], rl(h, 44), _s); \
        _s = fmaf(Wlin[4], rl(h, 48), _s); \
        _s = fmaf(Wlin[5], rl(h, 52), _s); \
        if (lane == 0) out[b] = _s; \
    } \
} while (0)

#define ENTRY(IT0) do { \
    const int _slot = ((IT0) + 32 + L) & 63; \
    _Pragma("unroll") \
    for (int _jj = 0; _jj < 12; ++_jj) { \
        float _v = acc[_jj] + lds[FBOFF + o * 12 + _jj]; \
        if (_jj < 6) _v = (o == 1) ? _v * 2.0f : _v; \
        lds[_slot * RPITCH + o * 12 + _jj] = _v; \
        acc[_jj] = 0.0f; \
    } \
    pc = pn; \
    pn = xb + (size_t)min((IT0) + 96 + L, TLEN - 1) * ISZ; \
} while (0)

    KC_HEAD(0);
    SPREAD_STEP(0, 0);
    {
        const float g  = loHalf ? xp_cur : base1;
        const float aG = fmaf(sgc, fast_sig(g), tgc);
        const float iq = qperm<0x00>(aG), gq = qperm<0xAA>(aG), oq = qperm<0xFF>(aG);
        const float cn = iq * gq;
        const float th = fmaf(2.0f, fast_sig(2.0f * cn), -1.0f);
        c = loHalf ? cn : 0.0f;
        h = loHalf ? (oq * th) : 0.0f;
        xp_cur = lds[RPITCH + r];
    }

    SPREAD_STEP(1, 0); SCAN_STEP(1);
    SPREAD_STEP(2, 0); SCAN_STEP(2);
    SPREAD_STEP(3, 0); SCAN_STEP(3);
    for (int kc = 1; kc < 8; ++kc) {
        KC_HEAD(kc);
        const int itb = kc << 2;
        SPREAD_STEP(0, kc); SCAN_STEP(itb + 0);
        SPREAD_STEP(1, kc); SCAN_STEP(itb + 1);
        SPREAD_STEP(2, kc); SCAN_STEP(itb + 2);
        SPREAD_STEP(3, kc); SCAN_STEP(itb + 3);
    }

    for (int w = 1; w < 7; ++w) {
        const int it0 = w << 5;
        ENTRY(it0);
        for (int kc = 0; kc < 8; ++kc) {
            const int itb = it0 + (kc << 2);
            if (itb > 200) break;
            KC_HEAD(kc);
            SPREAD_STEP(0, kc); SCAN_STEP(itb + 0);
            SPREAD_STEP(1, kc); SCAN_STEP(itb + 1);
            SPREAD_STEP(2, kc); SCAN_STEP(itb + 2);
            SPREAD_STEP(3, kc); SCAN_STEP(itb + 3);
        }
    }

#undef LDSW
#undef KC_HEAD
#undef SPREAD_STEP
#undef SCAN_STEP
#undef ENTRY
}

extern "C" void kernel_launch(void* const* d_in, const int* in_sizes, int n_in,
                              void* d_out, int out_size, void* d_ws, size_t ws_size,
                              hipStream_t stream) {
    const float* x    = (const float*)d_in[0];
    const float* Wih0 = (const float*)d_in[1];
    const float* Whh0 = (const float*)d_in[2];
    const float* bih0 = (const float*)d_in[3];
    const float* bhh0 = (const float*)d_in[4];
    const float* Wih1 = (const float*)d_in[5];
    const float* Whh1 = (const float*)d_in[6];
    const float* bih1 = (const float*)d_in[7];
    const float* bhh1 = (const float*)d_in[8];
    const float* Wlin = (const float*)d_in[9];
    const float* blin = (const float*)d_in[10];
    float* out = (float*)d_out;

    if (d_ws != nullptr && ws_size >= WS_REQ) {
        float4* xp4 = (float4*)d_ws;
        proj_k2<<<12800, 64, 0, stream>>>(x, Wih0, bih0, bhh0, bih1, bhh1, xp4);
        scan_k3<<<1024, 64, 0, stream>>>(Whh0, Wih1, Whh1, Wlin, blin,
                                         (const float4*)xp4, out);
    } else {
        lstm_fb<<<4096, 64, 0, stream>>>(x, Wih0, Whh0, bih0, bhh0,
                                         Wih1, Whh1, bih1, bhh1,
                                         Wlin, blin, out);
    }
}

// Round 6
// 274.283 us; speedup vs baseline: 1.0622x; 1.0622x over previous
//
#include <hip/hip_runtime.h>

// LSTM_67980742362036: 2-layer LSTM (B=4096, T=200, I=32, H=6) + linear head.
// R14:
//  proj_k3: weights-in-VGPR projection. R12 (weights from LDS: 96 ds_read/row)
//    and R13 (weights re-vector-loaded per row: SGPR=32 proved no scalarization)
//    both re-read the 3KB weight matrix ~200x/batch through a limited pipe.
//    Now lane g<48 holds weight row g%24 in 32 VGPRs (loaded ONCE); x is staged
//    coalesced into LDS (1KB/instr) and consumed via broadcast ds_reads
//    (2 distinct addrs/instr). Per 2-row iter: 8 ds_read_b128 + 32 FMA.
//  scan_k4: R12's proven swizzle step (48-weight table - smallest; R13's
//    64-entry rotation table spilled at VGPR=84 -> 1158cy/step) repackaged at
//    2 batches/wave: 2048 blocks -> 2 waves/SIMD. Model: issue 190cy/wave/step,
//    latency ~760cy -> wall max(2x190, 760/2) ~ 380-450cy (R12 at 1/SIMD was
//    latency-bound 764; R8 at 4/SIMD was issue-bound ~1594 w/ fat step).
//    Groups 2,3 inert: zero weights, bias-pinned xq stream, no stores.
// Fallback: proven R8 kernel (135.5us) if workspace too small.

#define TLEN  200
#define ISZ   32
#define HSZ   6
#define WPITCH 36

// ---- fallback (R8) LDS layout ----
#define RPITCH 25
#define RING_DW (64 * RPITCH)
#define FWOFF  RING_DW
#define FBOFF  (FWOFF + 24 * WPITCH)
#define FLDS_DW (FBOFF + 24)           // 9952 B

#define XP4_COUNT ((size_t)4096 * TLEN * 6)          // float4 elements
#define WS_REQ    ((XP4_COUNT + 6) * 16)             // + bias4 table

__device__ __forceinline__ float fast_sig(float x) {
    return __builtin_amdgcn_rcpf(1.0f + __expf(-x));
}
__device__ __forceinline__ float tanh_s(float x) {     // tanh via 2*sig(2x)-1
    return fmaf(2.0f, fast_sig(x + x), -1.0f);
}
__device__ __forceinline__ float rl(float v, int l) {
    return __int_as_float(__builtin_amdgcn_readlane(__float_as_int(v), l));
}
template <int CTRL>
__device__ __forceinline__ float qperm(float v) {
    return __int_as_float(__builtin_amdgcn_mov_dpp(__float_as_int(v), CTRL, 0xf, 0xf, true));
}
template <int OFF>
__device__ __forceinline__ float swz(float v) {        // BitMode group-broadcast
    return __int_as_float(__builtin_amdgcn_ds_swizzle(__float_as_int(v), OFF));
}
__device__ __forceinline__ float dot4(float4 w, float4 v) {
    return fmaf(w.x, v.x, fmaf(w.y, v.y, fmaf(w.z, v.z, w.w * v.w)));
}

// ======================= kernel 1: weights-in-VGPR projection =======================
__global__ __launch_bounds__(64) void proj_k3(
    const float* __restrict__ x,    const float* __restrict__ Wih0,
    const float* __restrict__ bih0, const float* __restrict__ bhh0,
    const float* __restrict__ bih1, const float* __restrict__ bhh1,
    float4* __restrict__ xp4)       // [b*200+t][u] (i,f,g,o); bias4 at XP4_COUNT
{
    __shared__ float xs[64 * 36];   // 64 staged x rows, pitch 36 dwords (9216 B)

    const int lane = threadIdx.x;
    const int b    = blockIdx.x;
    const float* xb = x + (size_t)b * TLEN * ISZ;

    if (b == 0 && lane < 24) {      // layer-1 folded bias table
        const int u = lane % 6, g = lane / 6;
        ((float*)(xp4 + XP4_COUNT))[u * 4 + g] = bih1[g * 6 + u] + bhh1[g * 6 + u];
    }

    // lane roles: s = row-parity (0/1), g = gate-row 0..23; lanes 48-63 idle
    const int s  = lane / 24;                    // 0,1,2(idle)
    const int se = (s == 2) ? 0 : s;
    const int g  = lane - s * 24;                // 0..23 (idle lanes: 0..15, harmless)
    const bool act = (lane < 48);

    // weight row W[g][0..31] resident in 32 VGPRs (loaded once)
    float4 w4[8];
    const float4* wr = (const float4*)(Wih0 + g * ISZ);
#pragma unroll
    for (int q = 0; q < 8; ++q) w4[q] = wr[q];
    const float bg = bih0[g] + bhh0[g];

    // output float offset within a 24-float row: u = g%6, comp = g/6
    const int ofs = (g % 6) * 4 + g / 6;
    float* xpb = (float*)(xp4 + (size_t)b * TLEN * 6);

#pragma unroll 1
    for (int tc = 0; tc < TLEN; tc += 64) {
        const int nrows = (TLEN - tc >= 64) ? 64 : (TLEN - tc);   // 64,64,64,8
        // ---- stage nrows x-rows, coalesced (consecutive float4 per lane) ----
        const float4* src = (const float4*)(xb + (size_t)tc * ISZ);
        for (int f = lane; f < nrows * 8; f += 64) {
            const int row = f >> 3, kq = f & 7;
            *(float4*)&xs[row * 36 + kq * 4] = src[f];
        }
        // single wave: DS pipe is in-order -> no barrier needed
        // ---- compute 2 rows per iteration (s selects row parity) ----
        const int half = nrows >> 1;
#pragma unroll 1
        for (int i = 0; i < half; ++i) {
            const int rr = 2 * i + se;
            float a0 = bg, a1 = 0.0f;
#pragma unroll
            for (int q = 0; q < 4; ++q) {
                const float4 xv = *(const float4*)&xs[rr * 36 + q * 4];
                a0 = fmaf(w4[q].x, xv.x, a0); a0 = fmaf(w4[q].y, xv.y, a0);
                a0 = fmaf(w4[q].z, xv.z, a0); a0 = fmaf(w4[q].w, xv.w, a0);
            }
#pragma unroll
            for (int q = 4; q < 8; ++q) {
                const float4 xv = *(const float4*)&xs[rr * 36 + q * 4];
                a1 = fmaf(w4[q].x, xv.x, a1); a1 = fmaf(w4[q].y, xv.y, a1);
                a1 = fmaf(w4[q].z, xv.z, a1); a1 = fmaf(w4[q].w, xv.w, a1);
            }
            const float a = a0 + a1;
            if (act) xpb[(size_t)(tc + rr) * 24 + ofs] = a;   // 2x96B segments/instr
        }
    }
}

// ======================= kernel 2: swizzle scan, 2 batches/wave =======================
__global__ __launch_bounds__(64) void scan_k4(
    const float* __restrict__ Whh0, const float* __restrict__ Wih1,
    const float* __restrict__ Whh1, const float* __restrict__ Wlin,
    const float* __restrict__ blin, const float4* __restrict__ xp4,
    float* __restrict__ out)
{
    const int lane = threadIdx.x;
    const int role = lane & 15;
    const int grp  = lane >> 4;
    const bool act = (grp < 2);                    // groups 2,3 inert
    const int b    = blockIdx.x * 2 + (grp & 1);

    // per-lane weights (R12 layout): WA = Whh0 (L0) / Wih1 (L1); WB = Whh1 (L1)
    float WA[4][6], WB[4][6];
#pragma unroll
    for (int gg = 0; gg < 4; ++gg)
#pragma unroll
        for (int k = 0; k < 6; ++k) { WA[gg][k] = 0.0f; WB[gg][k] = 0.0f; }
    if (act && role < 6) {
#pragma unroll
        for (int gg = 0; gg < 4; ++gg)
#pragma unroll
            for (int k = 0; k < 6; ++k) WA[gg][k] = Whh0[(gg * 6 + role) * 6 + k];
    } else if (act && role < 12) {
        const int u = role - 6;
#pragma unroll
        for (int gg = 0; gg < 4; ++gg)
#pragma unroll
            for (int k = 0; k < 6; ++k) {
                WA[gg][k] = Wih1[(gg * 6 + u) * 6 + k];
                WB[gg][k] = Whh1[(gg * 6 + u) * 6 + k];
            }
    }

    // xq stream: active L0 lanes walk xp4; all others pin a bias cell (ST=0)
    const float4* P;
    int ST;
    if (act && role < 6) { P = xp4 + (size_t)b * TLEN * 6 + role; ST = 6; }
    else { P = xp4 + XP4_COUNT + ((role >= 6 && role < 12) ? role - 6 : 0); ST = 0; }

    float4 q0 = P[0], q1 = P[ST], q2 = P[2 * ST], q3 = P[3 * ST];
    P += 4 * ST;

    float c = 0.0f, h = 0.0f;

#define ARG(A, G) do { \
    const float s0 = fmaf(WA[G][0], hA0, fmaf(WA[G][1], hA1, fmaf(WA[G][2], hA2, A))); \
    const float s1 = fmaf(WA[G][3], hA3, fmaf(WA[G][4], hA4, WA[G][5] * hA5)); \
    const float s2 = fmaf(WB[G][0], hB0, fmaf(WB[G][1], hB1, WB[G][2] * hB2)); \
    const float s3 = fmaf(WB[G][3], hB3, fmaf(WB[G][4], hB4, WB[G][5] * hB5)); \
    A = (s0 + s1) + (s2 + s3); \
} while (0)

#define STEP(XQ) do { \
    const float hA0 = swz<0x010>(h), hA1 = swz<0x030>(h), hA2 = swz<0x050>(h); \
    const float hA3 = swz<0x070>(h), hA4 = swz<0x090>(h), hA5 = swz<0x0B0>(h); \
    const float hB0 = swz<0x0D0>(h), hB1 = swz<0x0F0>(h), hB2 = swz<0x110>(h); \
    const float hB3 = swz<0x130>(h), hB4 = swz<0x150>(h), hB5 = swz<0x170>(h); \
    float a0 = (XQ).x, a1 = (XQ).y, a2 = (XQ).z, a3 = (XQ).w; \
    ARG(a0, 0); ARG(a1, 1); ARG(a2, 2); ARG(a3, 3); \
    const float ig = fast_sig(a0), fg = fast_sig(a1); \
    const float gg = tanh_s(a2),   og = fast_sig(a3); \
    c = fmaf(fg, c, ig * gg); \
    h = og * tanh_s(c); \
} while (0)

#define STEPR(QV) do { const float4 _xq = QV; QV = *P; P += ST; STEP(_xq); } while (0)

    // s = 0 peel; erase phantom state of roles >= 6 (h1(-1) = 0)   [R12 verbatim]
    STEPR(q0);
    h = (role < 6) ? h : 0.0f;
    c = (role < 6) ? c : 0.0f;

    // s = 1..192 (48 x 4 rotating 4-deep prefetch)
#pragma unroll 1
    for (int m = 0; m < 48; ++m) {
        STEPR(q1); STEPR(q2); STEPR(q3); STEPR(q0);
    }
    // s = 193..200 tail   [R12 verbatim]
    STEPR(q1); STEPR(q2); STEPR(q3);
    STEP(q0); STEP(q1); STEP(q2); STEP(q3);
    STEP(q0);

    // linear head: h2_last lives on roles 6..11
    {
        const float f0 = swz<0x0D0>(h), f1 = swz<0x0F0>(h), f2 = swz<0x110>(h);
        const float f3 = swz<0x130>(h), f4 = swz<0x150>(h), f5 = swz<0x170>(h);
        float sOut = blin[0];
        sOut = fmaf(Wlin[0], f0, sOut); sOut = fmaf(Wlin[1], f1, sOut);
        sOut = fmaf(Wlin[2], f2, sOut); sOut = fmaf(Wlin[3], f3, sOut);
        sOut = fmaf(Wlin[4], f4, sOut); sOut = fmaf(Wlin[5], f5, sOut);
        if (act && role == 0) out[b] = sOut;
    }
#undef STEP
#undef STEPR
#undef ARG
}

// ======================= fallback: proven R8 kernel (135.5 us) =======================
__global__ __launch_bounds__(64) void lstm_fb(
    const float* __restrict__ x,
    const float* __restrict__ Wih0, const float* __restrict__ Whh0,
    const float* __restrict__ bih0, const float* __restrict__ bhh0,
    const float* __restrict__ Wih1, const float* __restrict__ Whh1,
    const float* __restrict__ bih1, const float* __restrict__ bhh1,
    const float* __restrict__ Wlin, const float* __restrict__ blin,
    float* __restrict__ out)
{
    __shared__ float lds[FLDS_DW];

    const int lane = threadIdx.x;
    const int b    = blockIdx.x;

    const int o = lane & 1;
    const int L = lane >> 1;

    const bool loHalf = (lane < 32);
    const int  p  = lane & 3;
    const int  jq = (lane & 31) >> 2;
    const int  j  = (jq < HSZ) ? jq : 0;
    const int  r  = 6 * p + j;

#define LDSW(ROW, KCQ) (*(const float4*)&lds[FWOFF + (o * 12 + (ROW)) * WPITCH + ((KCQ) << 2)])

#pragma unroll
    for (int k = 0; k < 13; ++k) {
        const int idx = lane + (k << 6);
        if (idx < 768) {
            const int row = idx >> 5, kk = idx & 31;
            lds[FWOFF + row * WPITCH + kk] = Wih0[idx];
        } else if (idx < 792) {
            lds[FBOFF + idx - 768] = bih0[idx - 768] + bhh0[idx - 768];
        }
    }

    float WA[6], WB[6], base1 = 0.0f, sgc = 1.0f, tgc = 0.0f;
#pragma unroll
    for (int k = 0; k < 6; ++k) { WA[k] = 0.0f; WB[k] = 0.0f; }
    if (loHalf) {
#pragma unroll
        for (int k = 0; k < 6; ++k) WA[k] = Whh0[r * 6 + k];
    } else {
#pragma unroll
        for (int k = 0; k < 6; ++k) { WA[k] = Wih1[r * 6 + k]; WB[k] = Whh1[r * 6 + k]; }
        base1 = bih1[r] + bhh1[r];
    }
    if (p == 2) {
#pragma unroll
        for (int k = 0; k < 6; ++k) { WA[k] *= 2.0f; WB[k] *= 2.0f; }
        base1 *= 2.0f; sgc = 2.0f; tgc = -1.0f;
    }

    const float* xb = x + (size_t)b * TLEN * ISZ;

#pragma unroll
    for (int w01 = 0; w01 < 2; ++w01) {
        const int t = (w01 << 5) + L;
        const float4* xr4 = (const float4*)(xb + t * ISZ);
        float4 xw[8];
#pragma unroll
        for (int q = 0; q < 8; ++q) xw[q] = xr4[q];
        float a0c[12];
#pragma unroll
        for (int jj = 0; jj < 12; ++jj) a0c[jj] = 0.0f;
#pragma unroll
        for (int kc = 0; kc < 8; ++kc)
#pragma unroll
            for (int jj = 0; jj < 12; ++jj)
                a0c[jj] += dot4(LDSW(jj, kc), xw[kc]);
#pragma unroll
        for (int jj = 0; jj < 12; ++jj) {
            float v = a0c[jj] + lds[FBOFF + o * 12 + jj];
            if (jj < 6) v = (o == 1) ? v * 2.0f : v;
            lds[t * RPITCH + o * 12 + jj] = v;
        }
    }

    float acc[12];
#pragma unroll
    for (int jj = 0; jj < 12; ++jj) acc[jj] = 0.0f;
    const float* pc = xb + (size_t)min(64 + L, TLEN - 1) * ISZ;
    const float* pn = xb + (size_t)min(96 + L, TLEN - 1) * ISZ;
    float4 f0, f1;
    f1 = *((const float4*)pc);
    float4 Wp0 = LDSW(0, 0), Wp1 = LDSW(1, 0), Wp2 = LDSW(2, 0);

    float c = 0.0f, h = 0.0f;
    float xp_cur = lds[r];

#define KC_HEAD(KC) do { \
    f0 = f1; \
    const float4* _srcp = ((KC) < 7) ? ((const float4*)pc + (KC) + 1) \
                                     : ((const float4*)pn); \
    f1 = *_srcp; \
} while (0)

#define SPREAD_STEP(RT, KC) do { \
    acc[3*(RT)+0] += dot4(Wp0, f0); \
    acc[3*(RT)+1] += dot4(Wp1, f0); \
    acc[3*(RT)+2] += dot4(Wp2, f0); \
    const int _rtn = ((RT) + 1) & 3; \
    const int _kcn = ((RT) == 3) ? (((KC) + 1) & 7) : (KC); \
    Wp0 = LDSW(3*_rtn + 0, _kcn); \
    Wp1 = LDSW(3*_rtn + 1, _kcn); \
    Wp2 = LDSW(3*_rtn + 2, _kcn); \
} while (0)

#define SCAN_STEP(ITV) do { \
    const float h10=rl(h,0),  h11=rl(h,4),  h12=rl(h,8); \
    const float h13=rl(h,12), h14=rl(h,16), h15=rl(h,20); \
    const float h20=rl(h,32), h21=rl(h,36), h22=rl(h,40); \
    const float h23=rl(h,44), h24=rl(h,48), h25=rl(h,52); \
    const float _xn = lds[(((ITV) + 1) & 63) * RPITCH + r]; \
    const float _g0 = loHalf ? xp_cur : base1; \
    const float _a0 = fmaf(WA[0],h10, fmaf(WA[2],h12, fmaf(WA[4],h14, _g0))); \
    const float _a1 = fmaf(WA[1],h11, fmaf(WA[3],h13, WA[5]*h15)); \
    const float _b0 = fmaf(WB[0],h20, fmaf(WB[2],h22, WB[4]*h24)); \
    const float _b1 = fmaf(WB[1],h21, fmaf(WB[3],h23, WB[5]*h25)); \
    const float _g  = (_a0 + _a1) + (_b0 + _b1); \
    const float _aG = fmaf(sgc, fast_sig(_g), tgc); \
    const float _iq = qperm<0x00>(_aG), _fq = qperm<0x55>(_aG); \
    const float _gq = qperm<0xAA>(_aG), _oq = qperm<0xFF>(_aG); \
    c = fmaf(_fq, c, _iq * _gq); \
    const float _th = fmaf(2.0f, fast_sig(2.0f * c), -1.0f); \
    h = _oq * _th; \
    xp_cur = _xn; \
    if ((ITV) == 200) { \
        float _s = blin[0]; \
        _s = fmaf(Wlin[0], rl(h, 32), _s); \
        _s = fmaf(Wlin[1], rl(h, 36), _s); \
        _s = fmaf(Wlin[2], rl(h, 40), _s); \
        _s = fmaf(Wlin[3], rl(h, 44), _s); \
        _s = fmaf(Wlin[4], rl(h, 48), _s); \
        _s = fmaf(Wlin[5], rl(h, 52), _s); \
        if (lane == 0) out[b] = _s; \
    } \
} while (0)

#define ENTRY(IT0) do { \
    const int _slot = ((IT0) + 32 + L) & 63; \
    _Pragma("unroll") \
    for (int _jj = 0; _jj < 12; ++_jj) { \
        float _v = acc[_jj] + lds[FBOFF + o * 12 + _jj]; \
        if (_jj < 6) _v = (o == 1) ? _v * 2.0f : _v; \
        lds[_slot * RPITCH + o * 12 + _jj] = _v; \
        acc[_jj] = 0.0f; \
    } \
    pc = pn; \
    pn = xb + (size_t)min((IT0) + 96 + L, TLEN - 1) * ISZ; \
} while (0)

    KC_HEAD(0);
    SPREAD_STEP(0, 0);
    {
        const float g  = loHalf ? xp_cur : base1;
        const float aG = fmaf(sgc, fast_sig(g), tgc);
        const float iq = qperm<0x00>(aG), gq = qperm<0xAA>(aG), oq = qperm<0xFF>(aG);
        const float cn = iq * gq;
        const float th = fmaf(2.0f, fast_sig(2.0f * cn), -1.0f);
        c = loHalf ? cn : 0.0f;
        h = loHalf ? (oq * th) : 0.0f;
        xp_cur = lds[RPITCH + r];
    }

    SPREAD_STEP(1, 0); SCAN_STEP(1);
    SPREAD_STEP(2, 0); SCAN_STEP(2);
    SPREAD_STEP(3, 0); SCAN_STEP(3);
    for (int kc = 1; kc < 8; ++kc) {
        KC_HEAD(kc);
        const int itb = kc << 2;
        SPREAD_STEP(0, kc); SCAN_STEP(itb + 0);
        SPREAD_STEP(1, kc); SCAN_STEP(itb + 1);
        SPREAD_STEP(2, kc); SCAN_STEP(itb + 2);
        SPREAD_STEP(3, kc); SCAN_STEP(itb + 3);
    }

    for (int w = 1; w < 7; ++w) {
        const int it0 = w << 5;
        ENTRY(it0);
        for (int kc = 0; kc < 8; ++kc) {
            const int itb = it0 + (kc << 2);
            if (itb > 200) break;
            KC_HEAD(kc);
            SPREAD_STEP(0, kc); SCAN_STEP(itb + 0);
            SPREAD_STEP(1, kc); SCAN_STEP(itb + 1);
            SPREAD_STEP(2, kc); SCAN_STEP(itb + 2);
            SPREAD_STEP(3, kc); SCAN_STEP(itb + 3);
        }
    }

#undef LDSW
#undef KC_HEAD
#undef SPREAD_STEP
#undef SCAN_STEP
#undef ENTRY
}

extern "C" void kernel_launch(void* const* d_in, const int* in_sizes, int n_in,
                              void* d_out, int out_size, void* d_ws, size_t ws_size,
                              hipStream_t stream) {
    const float* x    = (const float*)d_in[0];
    const float* Wih0 = (const float*)d_in[1];
    const float* Whh0 = (const float*)d_in[2];
    const float* bih0 = (const float*)d_in[3];
    const float* bhh0 = (const float*)d_in[4];
    const float* Wih1 = (const float*)d_in[5];
    const float* Whh1 = (const float*)d_in[6];
    const float* bih1 = (const float*)d_in[7];
    const float* bhh1 = (const float*)d_in[8];
    const float* Wlin = (const float*)d_in[9];
    const float* blin = (const float*)d_in[10];
    float* out = (float*)d_out;

    if (d_ws != nullptr && ws_size >= WS_REQ) {
        float4* xp4 = (float4*)d_ws;
        proj_k3<<<4096, 64, 0, stream>>>(x, Wih0, bih0, bhh0, bih1, bhh1, xp4);
        scan_k4<<<2048, 64, 0, stream>>>(Whh0, Wih1, Whh1, Wlin, blin,
                                         (const float4*)xp4, out);
    } else {
        lstm_fb<<<4096, 64, 0, stream>>>(x, Wih0, Whh0, bih0, bhh0,
                                         Wih1, Whh1, bih1, bhh1,
                                         Wlin, blin, out);
    }
}